// Round 3
// baseline (1403.910 us; speedup 1.0000x reference)
//
#include <hip/hip_runtime.h>
#include <stdint.h>

#define HID 2048
#define HKK 8                          // HID / (64 lanes * 4 floats)
#define HSQ ((size_t)HID * HID)        // one gate-block of a weight matrix
#define LSTR ((size_t)4 * HID * HID)   // per-layer stride of W_ih/W_hh
#define GROWS (4 * HID)                // 8192 gate-rows per matrix
#define NOPS 8

// ws layout (float offsets)
#define OFF_H0   0                     // [2][HID] ping-pong
#define OFF_H1   4096                  // [HID]
#define OFF_C0   6144                  // [HID]
#define OFF_C1   8192                  // [HID]
#define OFF_P1   10240                 // [GROWS] layer-1 partial gates
#define OFF_SC   18432                 // lp, ent, sel(int), pad
#define OFF_PIH  18436                 // [9][GROWS] W_ih0@emb + b0 (PRE)
#define WS_FLOATS (OFF_PIH + 9 * GROWS)

__device__ __forceinline__ uint32_t rotl32_(uint32_t v, int d) {
  return (v << d) | (v >> (32 - d));
}

// JAX threefry2x32, 20 rounds, key (k0,k1), counter (x0,x1)
__device__ __forceinline__ void tf2x32(uint32_t k0, uint32_t k1,
                                       uint32_t x0, uint32_t x1,
                                       uint32_t& o0, uint32_t& o1) {
  uint32_t k2 = k0 ^ k1 ^ 0x1BD11BDAu;
  x0 += k0; x1 += k1;
#define TFR(r) { x0 += x1; x1 = rotl32_(x1, r); x1 ^= x0; }
  TFR(13) TFR(15) TFR(26) TFR(6)
  x0 += k1; x1 += k2 + 1u;
  TFR(17) TFR(29) TFR(16) TFR(24)
  x0 += k2; x1 += k0 + 2u;
  TFR(13) TFR(15) TFR(26) TFR(6)
  x0 += k0; x1 += k1 + 3u;
  TFR(17) TFR(29) TFR(16) TFR(24)
  x0 += k1; x1 += k2 + 4u;
  TFR(13) TFR(15) TFR(26) TFR(6)
  x0 += k2; x1 += k0 + 5u;
#undef TFR
  o0 = x0; o1 = x1;
}

__device__ __forceinline__ float sigm_(float x) { return 1.0f / (1.0f + expf(-x)); }

__device__ __forceinline__ float wave_red(float s) {
#pragma unroll
  for (int o = 32; o > 0; o >>= 1) s += __shfl_xor(s, o, 64);
  return s;
}

// 4 gate-dots of one cell row: wrow + g*HSQ rows against vec (len HID).
__device__ __forceinline__ void dot4(const float* __restrict__ wrow,
                                     const float* __restrict__ vec,
                                     int lane, float* __restrict__ g4) {
  float4 acc[4];
#pragma unroll
  for (int g = 0; g < 4; ++g) acc[g] = make_float4(0.f, 0.f, 0.f, 0.f);
  for (int kk = 0; kk < HKK; ++kk) {
    const int off = kk * 256 + lane * 4;
    const float4 v = *(const float4*)(vec + off);
#pragma unroll
    for (int g = 0; g < 4; ++g) {
      const float4 w = *(const float4*)(wrow + (size_t)g * HSQ + off);
      acc[g].x = fmaf(w.x, v.x, acc[g].x);
      acc[g].y = fmaf(w.y, v.y, acc[g].y);
      acc[g].z = fmaf(w.z, v.z, acc[g].z);
      acc[g].w = fmaf(w.w, v.w, acc[g].w);
    }
  }
#pragma unroll
  for (int g = 0; g < 4; ++g) {
    float s = (acc[g].x + acc[g].y) + (acc[g].z + acc[g].w);
    g4[g] = wave_red(s);
  }
}

// zero h0(x2), h1, c0, c1, and lp/ent/sel scalars
__global__ __launch_bounds__(256) void k_init(float* __restrict__ ws) {
  const int gid = blockIdx.x * 256 + threadIdx.x;
  for (int i = gid; i < OFF_P1; i += gridDim.x * 256) ws[i] = 0.f;
  if (gid < 4) ws[OFF_SC + gid] = 0.f;
}

// pih[k][r] = W_ih0[r,:]@w_emb[k,:] + b_ih0[r] + b_hh0[r]; 8192 waves, 1 row each
__global__ __launch_bounds__(256) void k_pre(const float* __restrict__ w_emb,
                                             const float* __restrict__ W_ih,
                                             const float* __restrict__ b_ih,
                                             const float* __restrict__ b_hh,
                                             float* __restrict__ ws) {
  const int tid = threadIdx.x, lane = tid & 63, wv = tid >> 6;
  const int r = blockIdx.x * 4 + wv;  // 0..8191
  const float* wr = W_ih + (size_t)r * HID;
  float4 acc[NOPS + 1];
#pragma unroll
  for (int k = 0; k <= NOPS; ++k) acc[k] = make_float4(0.f, 0.f, 0.f, 0.f);
  for (int kk = 0; kk < HKK; ++kk) {
    const int off = kk * 256 + lane * 4;
    const float4 w = *(const float4*)(wr + off);
#pragma unroll
    for (int k = 0; k <= NOPS; ++k) {
      const float4 e = *(const float4*)(w_emb + (size_t)k * HID + off);
      acc[k].x = fmaf(w.x, e.x, acc[k].x);
      acc[k].y = fmaf(w.y, e.y, acc[k].y);
      acc[k].z = fmaf(w.z, e.z, acc[k].z);
      acc[k].w = fmaf(w.w, e.w, acc[k].w);
    }
  }
  const float bias = b_ih[r] + b_hh[r];
#pragma unroll
  for (int k = 0; k <= NOPS; ++k) {
    float s = (acc[k].x + acc[k].y) + (acc[k].z + acc[k].w);
    s = wave_red(s);
    if (lane == 0) ws[OFF_PIH + (size_t)k * GROWS + r] = s + bias;
  }
}

// Phase A: waves 0..2047 -> layer-0 cell update (uses pih or W_ih0@x);
//          waves 2048..4095 -> layer-1 recurrent partial p1 = W_hh1@h1 + b1.
template <bool PRE>
__global__ __launch_bounds__(256) void k_a(const float* __restrict__ W_ih,
                                           const float* __restrict__ W_hh,
                                           const float* __restrict__ w_emb,
                                           const float* __restrict__ b_ih,
                                           const float* __restrict__ b_hh,
                                           float* __restrict__ ws, int par,
                                           int dyn) {
  const int tid = threadIdx.x, lane = tid & 63, wv = tid >> 6;
  const int gw = blockIdx.x * 4 + wv;  // 0..4095
  const float* h0r = ws + OFF_H0 + par * HID;
  float*       h0w = ws + OFF_H0 + (par ^ 1) * HID;
  const float* h1  = ws + OFF_H1;

  if (gw < HID) {
    const int j = gw;
    const int sel = dyn ? *(const int*)(ws + OFF_SC + 2) : NOPS;
    float gate[4];
    dot4(W_hh + (size_t)j * HID, h0r, lane, gate);
    if constexpr (PRE) {
      const float* pih = ws + OFF_PIH + (size_t)sel * GROWS;
#pragma unroll
      for (int g = 0; g < 4; ++g) gate[g] += pih[g * HID + j];
    } else {
      float gi[4];
      dot4(W_ih + (size_t)j * HID, w_emb + (size_t)sel * HID, lane, gi);
#pragma unroll
      for (int g = 0; g < 4; ++g)
        gate[g] += gi[g] + b_ih[g * HID + j] + b_hh[g * HID + j];
    }
    if (lane == 0) {
      const float ig = sigm_(gate[0]);
      const float fg = sigm_(gate[1]);
      const float gg = tanhf(gate[2]);
      const float og = sigm_(gate[3]);
      const float c = fg * ws[OFF_C0 + j] + ig * gg;
      ws[OFF_C0 + j] = c;
      h0w[j] = og * tanhf(c);
    }
  } else {
    const int k = gw - HID;
    float gate[4];
    dot4(W_hh + LSTR + (size_t)k * HID, h1, lane, gate);
    if (lane == 0) {
#pragma unroll
      for (int g = 0; g < 4; ++g)
        ws[OFF_P1 + g * HID + k] =
            gate[g] + b_ih[GROWS + g * HID + k] + b_hh[GROWS + g * HID + k];
    }
  }
}

// Phase B: layer-1 finish: gates1 = p1 + W_ih1@h0_new; c1/h1 update.
__global__ __launch_bounds__(256) void k_b(const float* __restrict__ W_ih,
                                           float* __restrict__ ws, int par) {
  const int tid = threadIdx.x, lane = tid & 63, wv = tid >> 6;
  const int k = blockIdx.x * 4 + wv;  // 0..2047
  const float* h0n = ws + OFF_H0 + (par ^ 1) * HID;
  float gate[4];
  dot4(W_ih + LSTR + (size_t)k * HID, h0n, lane, gate);
  if (lane == 0) {
#pragma unroll
    for (int g = 0; g < 4; ++g) gate[g] += ws[OFF_P1 + g * HID + k];
    const float ig = sigm_(gate[0]);
    const float fg = sigm_(gate[1]);
    const float gg = tanhf(gate[2]);
    const float og = sigm_(gate[3]);
    const float c = fg * ws[OFF_C1 + k] + ig * gg;
    ws[OFF_C1 + k] = c;
    ws[OFF_H1 + k] = og * tanhf(c);
  }
}

// Phase C (flag steps only, 1 block): logits, gumbel sample, lp/ent, outputs.
__global__ __launch_bounds__(256) void k_c(const float* __restrict__ w_soft_w,
                                           const float* __restrict__ w_soft_b,
                                           float* __restrict__ out,
                                           float* __restrict__ ws, int t,
                                           int sidx, int K) {
  __shared__ float s_raw[NOPS];
  const int tid = threadIdx.x, lane = tid & 63, wv = tid >> 6;
  const float* h1 = ws + OFF_H1;
  const int r0 = wv * 2, r1 = r0 + 1;  // 4 waves x 2 rows = 8 logits
  float4 a0 = make_float4(0.f, 0.f, 0.f, 0.f);
  float4 a1 = make_float4(0.f, 0.f, 0.f, 0.f);
  for (int kk = 0; kk < HKK; ++kk) {
    const int off = kk * 256 + lane * 4;
    const float4 hv = *(const float4*)(h1 + off);
    const float4 wa = *(const float4*)(w_soft_w + (size_t)r0 * HID + off);
    const float4 wb = *(const float4*)(w_soft_w + (size_t)r1 * HID + off);
    a0.x = fmaf(wa.x, hv.x, a0.x); a0.y = fmaf(wa.y, hv.y, a0.y);
    a0.z = fmaf(wa.z, hv.z, a0.z); a0.w = fmaf(wa.w, hv.w, a0.w);
    a1.x = fmaf(wb.x, hv.x, a1.x); a1.y = fmaf(wb.y, hv.y, a1.y);
    a1.z = fmaf(wb.z, hv.z, a1.z); a1.w = fmaf(wb.w, hv.w, a1.w);
  }
  float s0 = wave_red((a0.x + a0.y) + (a0.z + a0.w));
  float s1 = wave_red((a1.x + a1.y) + (a1.z + a1.w));
  if (lane == 0) {
    s_raw[r0] = s0 + w_soft_b[r0];
    s_raw[r1] = s1 + w_soft_b[r1];
  }
  __syncthreads();
  if (tid == 0) {
    float logits[NOPS];
#pragma unroll
    for (int r = 0; r < NOPS; ++r) logits[r] = tanhf(s_raw[r] * 0.2f);
    // partitionable split: keys[t] = threefry(key=(0,1), cnt=(0,t))
    uint32_t k0, k1;
    tf2x32(0u, 1u, 0u, (uint32_t)t, k0, k1);
    // partitionable random_bits(key_t, 32, (8,)): bits[i] = o0^o1 @ cnt=(0,i)
    const float TINY = 1.17549435e-38f;
    int op = 0;
    float best = -1e30f;
#pragma unroll
    for (int r = 0; r < NOPS; ++r) {
      uint32_t o0, o1;
      tf2x32(k0, k1, 0u, (uint32_t)r, o0, o1);
      const uint32_t bits = o0 ^ o1;
      const float f = __uint_as_float((bits >> 9) | 0x3f800000u) - 1.0f;
      const float u = fmaxf(f + TINY, TINY);
      const float g = -logf(-logf(u));
      const float y = g + logits[r];
      if (y > best) { best = y; op = r; }  // first-max (jnp.argmax)
    }
    float mx = logits[0];
#pragma unroll
    for (int r = 1; r < NOPS; ++r) mx = fmaxf(mx, logits[r]);
    float se = 0.f;
#pragma unroll
    for (int r = 0; r < NOPS; ++r) se += expf(logits[r] - mx);
    const float lse = mx + logf(se);
    const float lp = ws[OFF_SC] + (logits[op] - lse);
    float es = 0.f;
#pragma unroll
    for (int r = 0; r < NOPS; ++r) {
      const float lr = logits[r] - lse;
      es += expf(lr) * lr;
    }
    const float ent = ws[OFF_SC + 1] - es;
    ws[OFF_SC] = lp;
    ws[OFF_SC + 1] = ent;
    *(int*)(ws + OFF_SC + 2) = op;
    out[sidx] = (float)op;
#pragma unroll
    for (int r = 0; r < NOPS; ++r) out[K + sidx * NOPS + r] = logits[r];
    out[9 * K] = lp;       // log_prob (last flag-step write wins)
    out[9 * K + 1] = ent;  // entropy
  }
}

extern "C" void kernel_launch(void* const* d_in, const int* in_sizes, int n_in,
                              void* d_out, int out_size, void* d_ws, size_t ws_size,
                              hipStream_t stream) {
  const float* w_emb    = (const float*)d_in[0];
  const float* W_ih     = (const float*)d_in[1];
  const float* W_hh     = (const float*)d_in[2];
  const float* b_ih     = (const float*)d_in[3];
  const float* b_hh     = (const float*)d_in[4];
  const float* w_soft_w = (const float*)d_in[5];
  const float* w_soft_b = (const float*)d_in[6];
  float* out            = (float*)d_out;
  float* ws             = (float*)d_ws;

  // out_size = 9*K + 2 -> K -> n_nodes; schedule is host-static.
  const int K = (out_size - 2) / 9;
  int n = 0;
  while (n * (n + 1) / 2 < K) ++n;
  const int T = 2 + K + n;

  int flags[192];
  {
    int idx = 0;
    flags[idx++] = 0;
    flags[idx++] = 0;
    for (int node = 0; node < n; ++node) {
      for (int i = 0; i <= node; ++i) flags[idx++] = 1;
      flags[idx++] = 0;
    }
  }

  const bool pre = ws_size >= (size_t)WS_FLOATS * sizeof(float);

  k_init<<<64, 256, 0, stream>>>(ws);
  if (pre) k_pre<<<2048, 256, 0, stream>>>(w_emb, W_ih, b_ih, b_hh, ws);

  int par = 0, sidx = 0, prevflag = 0;
  for (int t = 0; t < T; ++t) {
    if (pre)
      k_a<true><<<1024, 256, 0, stream>>>(W_ih, W_hh, w_emb, b_ih, b_hh, ws,
                                          par, prevflag);
    else
      k_a<false><<<1024, 256, 0, stream>>>(W_ih, W_hh, w_emb, b_ih, b_hh, ws,
                                           par, prevflag);
    k_b<<<512, 256, 0, stream>>>(W_ih, ws, par);
    if (flags[t]) {
      k_c<<<1, 256, 0, stream>>>(w_soft_w, w_soft_b, out, ws, t, sidx, K);
      ++sidx;
    }
    prevflag = flags[t];
    par ^= 1;
  }
}